// Round 1
// baseline (48211.438 us; speedup 1.0000x reference)
//
#include <hip/hip_runtime.h>
#include <math.h>

#define H        1024
#define TSTEPS   2048
#define NWG      256
#define NT       256
#define SEGS     16      // threads (column segments) per gate row
#define CPT      64      // columns per thread
#define PAD      68      // padded segment stride (floats) -> 2-way bank alias (free)

__device__ __forceinline__ float sigmoidf_(float x) { return 1.0f / (1.0f + expf(-x)); }

__device__ __forceinline__ void grid_sync(unsigned* flags, unsigned target, int tid) {
    __syncthreads();
    if (tid == 0) {
        __hip_atomic_store(flags + blockIdx.x, target, __ATOMIC_RELEASE,
                           __HIP_MEMORY_SCOPE_AGENT);
    }
    // every thread polls one WG's flag -> full happens-before web, no contention
    while (__hip_atomic_load(flags + tid, __ATOMIC_ACQUIRE,
                             __HIP_MEMORY_SCOPE_AGENT) < target) { }
    __syncthreads();
}

__global__ __launch_bounds__(NT, 1) void lstm_persistent(
    const float* __restrict__ z,   const float* __restrict__ Wih,
    const float* __restrict__ Whh, const float* __restrict__ b_ih,
    const float* __restrict__ b_hh,
    const float* __restrict__ W1,  const float* __restrict__ b1,
    const float* __restrict__ W2,  const float* __restrict__ b2,
    const float* __restrict__ W3,  const float* __restrict__ b3,
    float* __restrict__ out, float* __restrict__ hs, unsigned* __restrict__ flags)
{
    __shared__ __align__(16) float h_lds[SEGS * PAD];  // padded h staging
    __shared__ float gate_lds[16];
    __shared__ float bias_lds[16];
    __shared__ float c_lds[4];
    __shared__ float a1_lds[32];
    __shared__ float a2_lds[32];

    const int tid = threadIdx.x;
    const int wg  = blockIdx.x;
    const int r   = tid >> 4;         // local gate row 0..15
    const int seg = tid & 15;         // column segment 0..15
    const int e   = r & 3;            // h-element within WG (0..3)
    const int g   = r >> 2;           // gate index: 0=i,1=f,2=g,3=o
    const int grow = g * H + wg * 4 + e;   // global gate row

    // ---- stage z into padded LDS; biases ----
    {
        float4 zv = *(const float4*)(z + tid * 4);
        *(float4*)(h_lds + (tid >> 4) * PAD + (tid & 15) * 4) = zv;
    }
    if (tid < 16) {
        int ee = tid & 3, gg = tid >> 2;
        int gr = gg * H + wg * 4 + ee;
        bias_lds[tid] = b_ih[gr] + b_hh[gr];
    }
    __syncthreads();

    // ---- load combined weights into registers; fuse step-0 dot (Wih @ z) ----
    float4 wreg[16];
    float acc = 0.f;
    const float* wih_p = Wih + (size_t)grow * H + seg * CPT;
    const float* whh_p = Whh + (size_t)grow * H + seg * CPT;
#pragma unroll
    for (int k = 0; k < 16; ++k) {
        float4 a = *(const float4*)(wih_p + 4 * k);
        float4 b = *(const float4*)(whh_p + 4 * k);
        float4 zz = *(const float4*)(h_lds + seg * PAD + 4 * k);
        acc += a.x * zz.x + a.y * zz.y + a.z * zz.z + a.w * zz.w;
        wreg[k] = make_float4(a.x + b.x, a.y + b.y, a.z + b.z, a.w + b.w);
    }
    // reduce over 16 segment lanes
    acc += __shfl_xor(acc, 1);  acc += __shfl_xor(acc, 2);
    acc += __shfl_xor(acc, 4);  acc += __shfl_xor(acc, 8);
    if (seg == 0) gate_lds[r] = acc + bias_lds[r];
    __syncthreads();
    if (tid < 4) {  // step-0 cell update (c_prev = 0)
        float iv = gate_lds[tid],      fv = gate_lds[4 + tid];
        float gv = gate_lds[8 + tid],  ov = gate_lds[12 + tid];
        float c = sigmoidf_(iv) * tanhf(gv);   // sig(f)*0 dropped
        (void)fv;
        float h = sigmoidf_(ov) * tanhf(c);
        c_lds[tid] = c;
        hs[wg * 4 + tid] = h;
    }
    grid_sync(flags, 1u, tid);

    // ---- main recurrence: gates = Wc @ h(t-1) + bias ----
    for (int t = 1; t < TSTEPS; ++t) {
        float4 hv = *(const float4*)(hs + (size_t)(t - 1) * H + tid * 4);
        *(float4*)(h_lds + (tid >> 4) * PAD + (tid & 15) * 4) = hv;
        __syncthreads();

        float a2 = 0.f;
#pragma unroll
        for (int k = 0; k < 16; ++k) {
            float4 h4 = *(const float4*)(h_lds + seg * PAD + 4 * k);
            float4 w  = wreg[k];
            a2 += w.x * h4.x + w.y * h4.y + w.z * h4.z + w.w * h4.w;
        }
        a2 += __shfl_xor(a2, 1);  a2 += __shfl_xor(a2, 2);
        a2 += __shfl_xor(a2, 4);  a2 += __shfl_xor(a2, 8);
        if (seg == 0) gate_lds[r] = a2 + bias_lds[r];
        __syncthreads();

        if (tid < 4) {
            float iv = gate_lds[tid],      fv = gate_lds[4 + tid];
            float gv = gate_lds[8 + tid],  ov = gate_lds[12 + tid];
            float c = sigmoidf_(fv) * c_lds[tid] + sigmoidf_(iv) * tanhf(gv);
            float h = sigmoidf_(ov) * tanhf(c);
            c_lds[tid] = c;
            hs[(size_t)t * H + wg * 4 + tid] = h;
        }
        grid_sync(flags, (unsigned)(t + 1), tid);
    }

    // ---- MLP tail: each WG handles 8 timesteps ----
    const int row = tid >> 3;   // 0..31
    const int sub = tid & 7;    // 0..7
    for (int ti = 0; ti < 8; ++ti) {
        int t = wg * 8 + ti;
        float4 hv = *(const float4*)(hs + (size_t)t * H + tid * 4);
        __syncthreads();  // previous iteration fully done with LDS
        *(float4*)(h_lds + (tid >> 4) * PAD + (tid & 15) * 4) = hv;
        __syncthreads();

        // a1 = relu(W1 @ h + b1): 32 rows x 8 lanes x 128 cols
        float acc1 = 0.f;
        const float* w1p = W1 + (size_t)row * H + sub * 128;
#pragma unroll
        for (int k = 0; k < 32; ++k) {
            float4 wv = *(const float4*)(w1p + 4 * k);
            int c = sub * 128 + 4 * k;
            float4 h4 = *(const float4*)(h_lds + (c >> 6) * PAD + (c & 63));
            acc1 += wv.x * h4.x + wv.y * h4.y + wv.z * h4.z + wv.w * h4.w;
        }
        acc1 += __shfl_xor(acc1, 1); acc1 += __shfl_xor(acc1, 2); acc1 += __shfl_xor(acc1, 4);
        if (sub == 0) a1_lds[row] = fmaxf(acc1 + b1[row], 0.f);
        __syncthreads();

        if (tid < 32) {
            float a = 0.f;
#pragma unroll
            for (int k = 0; k < 32; ++k) a += W2[tid * 32 + k] * a1_lds[k];
            a2_lds[tid] = fmaxf(a + b2[tid], 0.f);
        }
        __syncthreads();

        if (tid < 64) {
            float a = 0.f;
#pragma unroll
            for (int k = 0; k < 32; ++k) a += W3[tid * 32 + k] * a2_lds[k];
            out[(size_t)t * 64 + tid] = a + b3[tid];
        }
    }
}

extern "C" void kernel_launch(void* const* d_in, const int* in_sizes, int n_in,
                              void* d_out, int out_size, void* d_ws, size_t ws_size,
                              hipStream_t stream) {
    const float* z    = (const float*)d_in[0];
    const float* Wih  = (const float*)d_in[1];
    const float* Whh  = (const float*)d_in[2];
    const float* b_ih = (const float*)d_in[3];
    const float* b_hh = (const float*)d_in[4];
    const float* W1   = (const float*)d_in[5];
    const float* b1   = (const float*)d_in[6];
    const float* W2   = (const float*)d_in[7];
    const float* b2   = (const float*)d_in[8];
    const float* W3   = (const float*)d_in[9];
    const float* b3   = (const float*)d_in[10];
    float* out = (float*)d_out;

    unsigned char* ws = (unsigned char*)d_ws;
    unsigned* flags = (unsigned*)ws;                 // NWG u32
    float*    hs    = (float*)(ws + 4096);           // TSTEPS * H floats = 8 MB

    hipMemsetAsync(flags, 0, NWG * sizeof(unsigned), stream);
    hipLaunchKernelGGL(lstm_persistent, dim3(NWG), dim3(NT), 0, stream,
                       z, Wih, Whh, b_ih, b_hh, W1, b1, W2, b2, W3, b3,
                       out, hs, flags);
}

// Round 2
// 5487.246 us; speedup vs baseline: 8.7861x; 8.7861x over previous
//
#include <hip/hip_runtime.h>
#include <math.h>

#define H        1024
#define TSTEPS   2048
#define NWG      256
#define NT       256
#define SEGS     16      // threads (column segments) per gate row
#define CPT      64      // columns per thread
#define PAD      68      // padded segment stride (floats)
#define SENT     0xFFFFFFFFu   // -NaN bit pattern: h,z can never be this

__device__ __forceinline__ float sigmoidf_(float x) { return 1.0f / (1.0f + expf(-x)); }

// Poll 16 B of a row (this thread's slice) until no dword is the sentinel,
// then stage into padded LDS. Relaxed AGENT atomics: per-access L1/L2 bypass,
// no cache-maintenance instructions in the loop.
__device__ __forceinline__ void load_row_poll(const float* rowp, float* h_lds, int tid) {
    const unsigned long long* p = (const unsigned long long*)(rowp + 4 * tid);
    unsigned long long v0, v1;
    int spin = 0;
    for (;;) {
        v0 = __hip_atomic_load(p,     __ATOMIC_RELAXED, __HIP_MEMORY_SCOPE_AGENT);
        v1 = __hip_atomic_load(p + 1, __ATOMIC_RELAXED, __HIP_MEMORY_SCOPE_AGENT);
        if (((unsigned)v0 != SENT) && ((unsigned)(v0 >> 32) != SENT) &&
            ((unsigned)v1 != SENT) && ((unsigned)(v1 >> 32) != SENT)) break;
        if (((++spin) & 1023) == 0) __threadfence();  // anti-hang insurance, rare
    }
    float4 hv;
    hv.x = __uint_as_float((unsigned)v0);
    hv.y = __uint_as_float((unsigned)(v0 >> 32));
    hv.z = __uint_as_float((unsigned)v1);
    hv.w = __uint_as_float((unsigned)(v1 >> 32));
    *(float4*)(h_lds + (tid >> 4) * PAD + (tid & 15) * 4) = hv;
}

__global__ __launch_bounds__(NT, 1) void lstm_persistent(
    const float* __restrict__ z,   const float* __restrict__ Wih,
    const float* __restrict__ Whh, const float* __restrict__ b_ih,
    const float* __restrict__ b_hh,
    const float* __restrict__ W1,  const float* __restrict__ b1,
    const float* __restrict__ W2,  const float* __restrict__ b2,
    const float* __restrict__ W3,  const float* __restrict__ b3,
    float* __restrict__ out, float* __restrict__ hs)
{
    __shared__ __align__(16) float h_lds[SEGS * PAD];
    __shared__ float gate_lds[16];
    __shared__ float act_lds[16];
    __shared__ float bias_lds[16];
    __shared__ float a1_lds[32];
    __shared__ float a2_lds[32];

    const int tid = threadIdx.x;
    const int wg  = blockIdx.x;
    const int r   = tid >> 4;         // local gate row 0..15
    const int seg = tid & 15;         // column segment 0..15
    const int e   = r & 3;            // h-element within WG (0..3)
    const int g   = r >> 2;           // gate index: 0=i,1=f,2=g,3=o
    const int grow = g * H + wg * 4 + e;

    // ---- stage z into padded LDS; combined biases ----
    {
        float4 zv = *(const float4*)(z + tid * 4);
        *(float4*)(h_lds + (tid >> 4) * PAD + (tid & 15) * 4) = zv;
    }
    if (tid < 16) {
        int ee = tid & 3, gg = tid >> 2;
        int gr = gg * H + wg * 4 + ee;
        bias_lds[tid] = b_ih[gr] + b_hh[gr];
    }
    __syncthreads();

    // ---- load combined weights into registers; fuse step-0 dot (Wih @ z) ----
    float4 wreg[16];
    float acc = 0.f;
    const float* wih_p = Wih + (size_t)grow * H + seg * CPT;
    const float* whh_p = Whh + (size_t)grow * H + seg * CPT;
#pragma unroll
    for (int k = 0; k < 16; ++k) {
        float4 a = *(const float4*)(wih_p + 4 * k);
        float4 b = *(const float4*)(whh_p + 4 * k);
        float4 zz = *(const float4*)(h_lds + seg * PAD + 4 * k);
        acc += a.x * zz.x + a.y * zz.y + a.z * zz.z + a.w * zz.w;
        wreg[k] = make_float4(a.x + b.x, a.y + b.y, a.z + b.z, a.w + b.w);
    }
    acc += __shfl_xor(acc, 1);  acc += __shfl_xor(acc, 2);
    acc += __shfl_xor(acc, 4);  acc += __shfl_xor(acc, 8);
    if (seg == 0) gate_lds[r] = acc + bias_lds[r];
    __syncthreads();

    float c_reg = 0.f;   // valid for tid<4: cell state of element tid
    if (tid < 16) {
        float gv = gate_lds[tid];
        act_lds[tid] = ((tid & 12) == 8) ? tanhf(gv) : sigmoidf_(gv);
    }
    if (tid < 4) {       // step-0: c_prev = 0
        float c = act_lds[tid] * act_lds[8 + tid];
        float h = act_lds[12 + tid] * tanhf(c);
        c_reg = c;
        __hip_atomic_store((unsigned*)hs + wg * 4 + tid, __float_as_uint(h),
                           __ATOMIC_RELAXED, __HIP_MEMORY_SCOPE_AGENT);
    }

    // ---- main recurrence: dataflow-synced on sentinel-filled hs rows ----
    for (int t = 1; t < TSTEPS; ++t) {
        load_row_poll(hs + (size_t)(t - 1) * H, h_lds, tid);
        __syncthreads();                       // (A) h_lds filled

        float a2 = 0.f;
#pragma unroll
        for (int k = 0; k < 16; ++k) {
            float4 h4 = *(const float4*)(h_lds + seg * PAD + 4 * k);
            float4 w  = wreg[k];
            a2 += w.x * h4.x + w.y * h4.y + w.z * h4.z + w.w * h4.w;
        }
        a2 += __shfl_xor(a2, 1);  a2 += __shfl_xor(a2, 2);
        a2 += __shfl_xor(a2, 4);  a2 += __shfl_xor(a2, 8);
        if (seg == 0) gate_lds[r] = a2 + bias_lds[r];
        __syncthreads();                       // (B) gates ready

        if (tid < 16) {                        // wave 0: parallel transcendentals
            float gv = gate_lds[tid];
            act_lds[tid] = ((tid & 12) == 8) ? tanhf(gv) : sigmoidf_(gv);
        }
        if (tid < 4) {                         // same wave: ordered after act writes
            float c = act_lds[4 + tid] * c_reg + act_lds[tid] * act_lds[8 + tid];
            float h = act_lds[12 + tid] * tanhf(c);
            c_reg = c;
            __hip_atomic_store((unsigned*)(hs + (size_t)t * H) + wg * 4 + tid,
                               __float_as_uint(h),
                               __ATOMIC_RELAXED, __HIP_MEMORY_SCOPE_AGENT);
        }
    }

    // ---- MLP tail: each WG handles 8 timesteps; polling loader handles
    //      both late-arriving rows and cross-XCD visibility ----
    const int row = tid >> 3;   // 0..31
    const int sub = tid & 7;    // 0..7
    for (int ti = 0; ti < 8; ++ti) {
        int t = wg * 8 + ti;
        __syncthreads();                       // done with previous LDS contents
        load_row_poll(hs + (size_t)t * H, h_lds, tid);
        __syncthreads();

        float acc1 = 0.f;
        const float* w1p = W1 + (size_t)row * H + sub * 128;
#pragma unroll
        for (int k = 0; k < 32; ++k) {
            float4 wv = *(const float4*)(w1p + 4 * k);
            int c = sub * 128 + 4 * k;
            float4 h4 = *(const float4*)(h_lds + (c >> 6) * PAD + (c & 63));
            acc1 += wv.x * h4.x + wv.y * h4.y + wv.z * h4.z + wv.w * h4.w;
        }
        acc1 += __shfl_xor(acc1, 1); acc1 += __shfl_xor(acc1, 2); acc1 += __shfl_xor(acc1, 4);
        if (sub == 0) a1_lds[row] = fmaxf(acc1 + b1[row], 0.f);
        __syncthreads();

        if (tid < 32) {
            float a = 0.f;
#pragma unroll
            for (int k = 0; k < 32; ++k) a += W2[tid * 32 + k] * a1_lds[k];
            a2_lds[tid] = fmaxf(a + b2[tid], 0.f);
        }
        __syncthreads();

        if (tid < 64) {
            float a = 0.f;
#pragma unroll
            for (int k = 0; k < 32; ++k) a += W3[tid * 32 + k] * a2_lds[k];
            out[(size_t)t * 64 + tid] = a + b3[tid];
        }
    }
}

extern "C" void kernel_launch(void* const* d_in, const int* in_sizes, int n_in,
                              void* d_out, int out_size, void* d_ws, size_t ws_size,
                              hipStream_t stream) {
    const float* z    = (const float*)d_in[0];
    const float* Wih  = (const float*)d_in[1];
    const float* Whh  = (const float*)d_in[2];
    const float* b_ih = (const float*)d_in[3];
    const float* b_hh = (const float*)d_in[4];
    const float* W1   = (const float*)d_in[5];
    const float* b1   = (const float*)d_in[6];
    const float* W2   = (const float*)d_in[7];
    const float* b2   = (const float*)d_in[8];
    const float* W3   = (const float*)d_in[9];
    const float* b3   = (const float*)d_in[10];
    float* out = (float*)d_out;

    float* hs = (float*)d_ws;   // TSTEPS * H floats = 8 MB

    // Sentinel-fill hs: 0xFF bytes -> 0xFFFFFFFF (-NaN), unreachable as h.
    hipMemsetAsync(hs, 0xFF, (size_t)TSTEPS * H * sizeof(float), stream);
    hipLaunchKernelGGL(lstm_persistent, dim3(NWG), dim3(NT), 0, stream,
                       z, Wih, Whh, b_ih, b_hh, W1, b1, W2, b2, W3, b3,
                       out, hs);
}